// Round 8
// baseline (873.913 us; speedup 1.0000x reference)
//
#include <hip/hip_runtime.h>

// Problem dims (fixed by the reference setup)
#define Bn 8
#define Sn 2048
#define Dn 512
#define Gn 4
#define Cn 2048
#define DGn 128
#define Nn 16384  // B*S

// d_out layout (flat fp32, reference return order)
#define OFF_Q    0u        // quantize_st  [8,2048,512]  = 8388608
#define OFF_IND  8388608u  // ind_out      [8,2048,4]    = 65536 (float-encoded ints)
#define OFF_LOSS 8454144u  // commit_loss  scalar
#define OFF_CS   8454145u  // new_cluster_size [4,2048]  = 8192
#define OFF_AVG  8462337u  // new_embed_avg [4,2048,128] = 1048576
#define OFF_EMB  9510913u  // new_embed     [4,2048,128] = 1048576 (first 8192 temporarily hold ||E||^2)

__global__ void vq_init(const float* __restrict__ cs_in,
                        const float* __restrict__ avg_in,
                        float* __restrict__ out) {
    int i = blockIdx.x * 256 + threadIdx.x;
    if (i < Gn * Cn * DGn) out[OFF_AVG + i] = 0.8f * avg_in[i];
    if (i < Gn * Cn)       out[OFF_CS + i]  = 0.8f * cs_in[i];
    if (i == 0)            out[OFF_LOSS] = 0.0f;
}

// one wave per code row: ||E[g,c]||^2 -> stash at OFF_EMB (overwritten by finalize)
__global__ void vq_enorm(const float* __restrict__ embed,
                         float* __restrict__ out) {
    int gid  = blockIdx.x * 256 + threadIdx.x;
    int wave = gid >> 6;            // 0..8191
    int lane = gid & 63;
    const float* row = embed + (size_t)wave * DGn;
    float a = row[lane], b = row[lane + 64];
    float v = fmaf(a, a, b * b);
    #pragma unroll
    for (int off = 32; off; off >>= 1) v += __shfl_xor(v, off, 64);
    if (lane == 0) out[OFF_EMB + wave] = v;
}

// Main fused kernel. Design facts from R4-R7 counters:
//  * 512-thread blocks cap at 1 block/CU regardless of LDS (R6 80K vs R7 72K:
//    both 23% occupancy) -> we own the CU: 2 waves/SIMD, full 160 KB LDS, and
//    a 256-VGPR cap per wave.
//  * Therefore: fat 8m x 16c fragment (128 acc VGPRs; 1.33 FMA per LDS byte ->
//    VALU-bound: LDS ~6400 cyc/stage < VALU 8192 cyc/stage), double-buffered
//    Es (one barrier per stage, 32 stages total vs R7's 256 barriers), and
//    T14 async staging: global->reg issued before compute, ds_write after.
//  * VALU floor: 524K cyc/CU = 218 us. k-accumulation order unchanged
//    (sequential 0..127) -> scores bit-identical to the passing R4/R6/R7.
__launch_bounds__(512, 1)
__global__ void vq_main(const float* __restrict__ x,
                        const float* __restrict__ embed,
                        float* __restrict__ out) {
    __shared__ float As[DGn][128];      // A transposed [k][m], 64 KB. bank = m%32 -> 2-way (free)
    __shared__ float Es[2][16][512];    // E k-slice dbuf [k][c], 64 KB. bank = c%32 -> 2-way (free)

    const int t  = threadIdx.x;
    const int g  = blockIdx.x >> 7;
    const int n0 = (blockIdx.x & 127) * 128;
    const int tr = t & 15;           // m-lane: 0..15
    const int tc = t >> 4;           // c-lane: 0..31

    const float* xg = x + (size_t)n0 * Dn + g * DGn;
    const float* eg = embed + (size_t)g * Cn * DGn;
    const float* enorm_g = out + OFF_EMB + g * Cn;

    // ---- stage A transposed: lane-per-row mapping -> scalar writes 2-way (free) ----
    {
        const int arow = t & 127, ah = t >> 7;   // ah: 0..3
        const float* xrow = xg + (size_t)arow * Dn;
        #pragma unroll
        for (int j = 0; j < 8; ++j) {
            int q4 = ah + 4 * j;
            float4 v = *(const float4*)(xrow + q4 * 4);
            int k = q4 * 4;
            As[k+0][arow] = v.x; As[k+1][arow] = v.y; As[k+2][arow] = v.z; As[k+3][arow] = v.w;
        }
    }
    // ---- prologue: stage E slice 0 (c0=0,k0=0) into buf 0 ----
    {
        const float* er = eg + (size_t)t * DGn;
        float4 p0 = *(const float4*)(er);
        float4 p1 = *(const float4*)(er + 4);
        float4 p2 = *(const float4*)(er + 8);
        float4 p3 = *(const float4*)(er + 12);
        Es[0][ 0][t] = p0.x; Es[0][ 1][t] = p0.y; Es[0][ 2][t] = p0.z; Es[0][ 3][t] = p0.w;
        Es[0][ 4][t] = p1.x; Es[0][ 5][t] = p1.y; Es[0][ 6][t] = p1.z; Es[0][ 7][t] = p1.w;
        Es[0][ 8][t] = p2.x; Es[0][ 9][t] = p2.y; Es[0][10][t] = p2.z; Es[0][11][t] = p2.w;
        Es[0][12][t] = p3.x; Es[0][13][t] = p3.y; Es[0][14][t] = p3.z; Es[0][15][t] = p3.w;
    }
    __syncthreads();

    float bestv[8];
    int   besti[8];
    #pragma unroll
    for (int i = 0; i < 8; ++i) { bestv[i] = -3.4e38f; besti[i] = 0; }

    const int m0 = 4 * tr;           // m-quads: m0 and 64+m0
    const int cb = 4 * tc;           // c-quads: cb + 128h, h=0..3 (512-wide c-tile)

    float acc[8][16];
    #pragma unroll
    for (int i = 0; i < 8; ++i)
        #pragma unroll
        for (int j = 0; j < 16; ++j) acc[i][j] = 0.f;

    // 32 stages: c0 = (s>>3)*512, k0 = (s&7)*16. One barrier per stage.
    for (int s = 0; s < 32; ++s) {
        const int cur = s & 1;
        const int c0 = (s >> 3) << 9;
        const int k0 = (s & 7) << 4;

        // T14: issue next slice's global loads before compute
        float4 p0, p1, p2, p3;
        if (s < 31) {
            const int s1 = s + 1;
            const int nc0 = (s1 >> 3) << 9;
            const int nk0 = (s1 & 7) << 4;
            const float* er = eg + (size_t)(nc0 + t) * DGn + nk0;
            p0 = *(const float4*)(er);
            p1 = *(const float4*)(er + 4);
            p2 = *(const float4*)(er + 8);
            p3 = *(const float4*)(er + 12);
        }

        #pragma unroll
        for (int kk = 0; kk < 16; ++kk) {
            float4 a0 = *(const float4*)&As[k0+kk][m0];
            float4 a1 = *(const float4*)&As[k0+kk][64 + m0];
            float4 b0 = *(const float4*)&Es[cur][kk][cb];
            float4 b1 = *(const float4*)&Es[cur][kk][128 + cb];
            float4 b2 = *(const float4*)&Es[cur][kk][256 + cb];
            float4 b3 = *(const float4*)&Es[cur][kk][384 + cb];
            float av[8]  = {a0.x,a0.y,a0.z,a0.w,a1.x,a1.y,a1.z,a1.w};
            float bv[16] = {b0.x,b0.y,b0.z,b0.w,b1.x,b1.y,b1.z,b1.w,
                            b2.x,b2.y,b2.z,b2.w,b3.x,b3.y,b3.z,b3.w};
            #pragma unroll
            for (int i = 0; i < 8; ++i) {
                float a = av[i];
                #pragma unroll
                for (int j = 0; j < 16; ++j)
                    acc[i][j] = fmaf(a, bv[j], acc[i][j]);
            }
        }

        // end of a c-iter: argmax, then reset acc. All indices compile-time.
        if ((s & 7) == 7) {
            #pragma unroll
            for (int h = 0; h < 4; ++h) {
                #pragma unroll
                for (int jj = 0; jj < 4; ++jj) {
                    int c = c0 + 128*h + cb + jj;
                    float en = enorm_g[c];
                    #pragma unroll
                    for (int i = 0; i < 8; ++i) {
                        float di = fmaf(2.0f, acc[i][4*h + jj], -en);
                        if (di > bestv[i]) { bestv[i] = di; besti[i] = c; }
                    }
                }
            }
            #pragma unroll
            for (int i = 0; i < 8; ++i)
                #pragma unroll
                for (int j = 0; j < 16; ++j) acc[i][j] = 0.f;
        }

        // write next slice into the other buffer (its readers finished at the
        // previous barrier), then one barrier.
        if (s < 31) {
            const int nxt = cur ^ 1;
            Es[nxt][ 0][t] = p0.x; Es[nxt][ 1][t] = p0.y; Es[nxt][ 2][t] = p0.z; Es[nxt][ 3][t] = p0.w;
            Es[nxt][ 4][t] = p1.x; Es[nxt][ 5][t] = p1.y; Es[nxt][ 6][t] = p1.z; Es[nxt][ 7][t] = p1.w;
            Es[nxt][ 8][t] = p2.x; Es[nxt][ 9][t] = p2.y; Es[nxt][10][t] = p2.z; Es[nxt][11][t] = p2.w;
            Es[nxt][12][t] = p3.x; Es[nxt][13][t] = p3.y; Es[nxt][14][t] = p3.z; Es[nxt][15][t] = p3.w;
        }
        __syncthreads();
    }

    // ---- cross-thread argmax reduce (alias dead As for red, dead Es for idxf) ----
    // stride 33: stride-32 would put bank = tc for all 16 writers -> 16-way.
    float* redv = &As[0][0];                 // 128*33 floats
    int*   redi = ((int*)&As[0][0]) + 4352;  // 128*33 ints
    int*   idxf = (int*)&Es[0][0][0];        // 128 ints
    #pragma unroll
    for (int i = 0; i < 8; ++i) {
        int m = (i < 4) ? (m0 + i) : (64 + m0 + i - 4);
        redv[m*33 + tc] = bestv[i];
        redi[m*33 + tc] = besti[i];
    }
    __syncthreads();
    if (t < 128) {
        float bv = redv[t*33]; int bi = redi[t*33];
        #pragma unroll
        for (int u = 1; u < 32; ++u) {
            float v2 = redv[t*33 + u]; int i2 = redi[t*33 + u];
            if (v2 > bv || (v2 == bv && i2 < bi)) { bv = v2; bi = i2; }
        }
        idxf[t] = bi;
        out[OFF_IND + (size_t)(n0 + t) * Gn + g] = (float)bi;
        atomicAdd(&out[OFF_CS + g*Cn + bi], 0.2f);
    }
    __syncthreads();

    // ---- quantize_st + embed_sum scatter + commit loss ----
    float lloss = 0.f;
    for (int j = 0; j < 32; ++j) {
        int e = j * 512 + t;
        int row = e >> 7, d = e & 127;
        int ci = idxf[row];
        float xv = xg[(size_t)row * Dn + d];
        float q  = eg[(size_t)ci * DGn + d];
        out[OFF_Q + (size_t)(n0+row) * Dn + g*DGn + d] = xv + (q - xv);
        atomicAdd(&out[OFF_AVG + ((size_t)g*Cn + ci)*DGn + d], 0.2f * xv);
        float df = q - xv;
        lloss += df * df;
    }
    #pragma unroll
    for (int off = 32; off; off >>= 1) lloss += __shfl_xor(lloss, off, 64);
    if ((t & 63) == 0) atomicAdd(&out[OFF_LOSS], lloss);
}

// per-g: total, laplace smoothing, new_embed = avg/smoothed; scale loss
__global__ void vq_finalize(float* __restrict__ out) {
    const int g = blockIdx.x >> 5;
    const int slice = blockIdx.x & 31;
    const int t = threadIdx.x;
    __shared__ float red[256];
    const float* ncs = out + OFF_CS + g * Cn;
    float s = 0.f;
    for (int c = t; c < Cn; c += 256) s += ncs[c];
    red[t] = s;
    __syncthreads();
    for (int w = 128; w; w >>= 1) {
        if (t < w) red[t] += red[t + w];
        __syncthreads();
    }
    float total = red[0];
    float denom = total + Cn * 1e-5f;
    const float* avg = out + OFF_AVG + (size_t)g * Cn * DGn;
    float* embo = out + OFF_EMB + (size_t)g * Cn * DGn;
    for (int u = 0; u < 32; ++u) {
        int e = slice * 8192 + u * 256 + t;
        int c = e >> 7;
        float sm = (ncs[c] + 1e-5f) / denom * total;
        embo[e] = avg[e] / sm;
    }
    if (blockIdx.x == 0 && t == 0) out[OFF_LOSS] *= (1.0f / 8388608.0f);
}

extern "C" void kernel_launch(void* const* d_in, const int* in_sizes, int n_in,
                              void* d_out, int out_size, void* d_ws, size_t ws_size,
                              hipStream_t stream) {
    const float* x    = (const float*)d_in[0];
    const float* emb  = (const float*)d_in[1];
    const float* cs   = (const float*)d_in[2];
    const float* eavg = (const float*)d_in[3];
    float* out = (float*)d_out;

    hipLaunchKernelGGL(vq_init,     dim3(4096), dim3(256), 0, stream, cs, eavg, out);
    hipLaunchKernelGGL(vq_enorm,    dim3(2048), dim3(256), 0, stream, emb, out);
    hipLaunchKernelGGL(vq_main,     dim3(512),  dim3(512), 0, stream, x, emb, out);
    hipLaunchKernelGGL(vq_finalize, dim3(128),  dim3(256), 0, stream, out);
}